// Round 5
// baseline (93.813 us; speedup 1.0000x reference)
//
#include <hip/hip_runtime.h>
#include <math.h>

#define BB 1024      // batch
#define DD 512       // feature dim
#define CC 50000     // classes
#define KMAX 1024    // max compacted classes
#define HSZ 2048     // hash size
#define SCALE_F 16.0f
#define EPS_F 0.1f

typedef __bf16 bf16_t;
typedef bf16_t bf16x2 __attribute__((ext_vector_type(2)));
typedef bf16_t bf16x8 __attribute__((ext_vector_type(8)));
typedef float f32x4 __attribute__((ext_vector_type(4)));

// ---------------- K1: dedup targets + SORT + ranks via binary search ---------
__global__ __launch_bounds__(1024) void k_prep(const int* __restrict__ targets,
                                               int* gkey, int* sc, int* rowrank,
                                               int* kctr, float* lossAcc,
                                               int* doneCtr) {
    __shared__ int hkey[HSZ];
    __shared__ int sorted[KMAX];
    __shared__ int kc;
    int tid = threadIdx.x;
    hkey[tid] = -1; hkey[tid + 1024] = -1;
    if (tid == 0) kc = 0;
    __syncthreads();
    int c = targets[tid];
    unsigned h = ((unsigned)c * 2654435761u) >> 21;   // 0..2047
    while (true) {
        int old = atomicCAS(&hkey[h], -1, c);
        if (old == -1) { sorted[atomicAdd(&kc, 1)] = c; break; }
        if (old == c) break;
        h = (h + 1) & (HSZ - 1);
    }
    __syncthreads();
    int kcv = kc;
    if (tid >= kcv) sorted[tid] = 0x7FFFFFFF;         // pad for bitonic
    __syncthreads();
    // bitonic sort, 1024 elements, ascending
    for (int size = 2; size <= KMAX; size <<= 1) {
        for (int stride = size >> 1; stride > 0; stride >>= 1) {
            int j = tid ^ stride;
            if (j > tid) {
                int a = sorted[tid], bv = sorted[j];
                bool asc = ((tid & size) == 0);
                if ((a > bv) == asc) { sorted[tid] = bv; sorted[j] = a; }
            }
            __syncthreads();
        }
    }
    sc[tid] = sorted[tid];                            // ascending seen classes
    // rank of own target via binary search (guaranteed present)
    int lo = 0, hi = kcv;
    while (lo < hi) {
        int mid = (lo + hi) >> 1;
        if (sorted[mid] < c) lo = mid + 1; else hi = mid;
    }
    rowrank[tid] = lo;
    gkey[tid] = hkey[tid]; gkey[tid + 1024] = hkey[tid + 1024];
    if (tid == 0) { *kctr = kcv; *lossAcc = 0.0f; *doneCtr = 0; }
}

// ---------------- K2: parallel lmem scan (appends non-target valid classes) --
__global__ void k_scan(const int* __restrict__ lmem,
                       const int* __restrict__ gkey,
                       int* sc, int* kctr) {
    int c = blockIdx.x * blockDim.x + threadIdx.x;
    if (c >= CC) return;
    if (lmem[c] == -1) return;            // all -1 in this workload: fast path
    unsigned h = ((unsigned)c * 2654435761u) >> 21;
    while (true) {
        int k = gkey[h];
        if (k == c) return;               // already ranked as a target class
        if (k == -1) break;               // absent from target set
        h = (h + 1) & (HSZ - 1);
    }
    int slot = atomicAdd(kctr, 1);
    if (slot < KMAX) sc[slot] = c;
}

// ---------------- K3: merged normalize (classes + rows) + bf16 hi/lo split ---
__global__ __launch_bounds__(256) void k_norm(const float* __restrict__ inputs,
                                              const float* __restrict__ fmem,
                                              const int* __restrict__ targets,
                                              const int* __restrict__ sc,
                                              const int* __restrict__ kctr,
                                              bf16_t* __restrict__ AH,
                                              bf16_t* __restrict__ AL,
                                              bf16_t* __restrict__ BH,
                                              bf16_t* __restrict__ BL) {
    int blk = blockIdx.x;
    int tid = threadIdx.x;
    int d0 = tid * 2;
    __shared__ float red[256];
    if (blk < KMAX) {
        // ---- class path: segment mean (sum; /count cancels) + normalize ----
        int k = blk;
        int Kv = *kctr; if (Kv > KMAX) Kv = KMAX;
        if (k >= Kv) {                    // zero-pad so GEMM reads zeros
            bf16x2 z; z[0] = (bf16_t)0.0f; z[1] = (bf16_t)0.0f;
            *(bf16x2*)(BH + k * DD + d0) = z;
            *(bf16x2*)(BL + k * DD + d0) = z;
            return;
        }
        int c = sc[k];
        __shared__ int members[BB];
        __shared__ int mcount;
        if (tid == 0) mcount = 0;
        __syncthreads();
        int4 t4 = *(const int4*)(targets + tid * 4);
        if (t4.x == c) { int s = atomicAdd(&mcount, 1); members[s] = tid * 4 + 0; }
        if (t4.y == c) { int s = atomicAdd(&mcount, 1); members[s] = tid * 4 + 1; }
        if (t4.z == c) { int s = atomicAdd(&mcount, 1); members[s] = tid * 4 + 2; }
        if (t4.w == c) { int s = atomicAdd(&mcount, 1); members[s] = tid * 4 + 3; }
        __syncthreads();
        int mc = mcount;
        float a0 = 0.0f, a1 = 0.0f;
        if (mc == 0) {                    // lmem-only class: memory row
            a0 = fmem[(size_t)c * DD + d0];
            a1 = fmem[(size_t)c * DD + d0 + 1];
        } else {
            for (int i = 0; i < mc; ++i) {
                int b = members[i];
                a0 += inputs[b * DD + d0];
                a1 += inputs[b * DD + d0 + 1];
            }
        }
        red[tid] = a0 * a0 + a1 * a1;
        __syncthreads();
        for (int s = 128; s > 0; s >>= 1) {
            if (tid < s) red[tid] += red[tid + s];
            __syncthreads();
        }
        float scale = 1.0f / fmaxf(sqrtf(red[0]), 1e-12f);
        a0 *= scale; a1 *= scale;
        bf16_t h0 = (bf16_t)a0, h1 = (bf16_t)a1;
        bf16x2 ph; ph[0] = h0; ph[1] = h1;
        bf16x2 pl; pl[0] = (bf16_t)(a0 - (float)h0); pl[1] = (bf16_t)(a1 - (float)h1);
        *(bf16x2*)(BH + k * DD + d0) = ph;
        *(bf16x2*)(BL + k * DD + d0) = pl;
    } else {
        // ---- row path: normalize input row ----
        int b = blk - KMAX;
        float a0 = inputs[b * DD + d0];
        float a1 = inputs[b * DD + d0 + 1];
        red[tid] = a0 * a0 + a1 * a1;
        __syncthreads();
        for (int s = 128; s > 0; s >>= 1) {
            if (tid < s) red[tid] += red[tid + s];
            __syncthreads();
        }
        float scale = 1.0f / fmaxf(sqrtf(red[0]), 1e-12f);
        a0 *= scale; a1 *= scale;
        bf16_t h0 = (bf16_t)a0, h1 = (bf16_t)a1;
        bf16x2 ph; ph[0] = h0; ph[1] = h1;
        bf16x2 pl; pl[0] = (bf16_t)(a0 - (float)h0); pl[1] = (bf16_t)(a1 - (float)h1);
        *(bf16x2*)(AH + b * DD + d0) = ph;
        *(bf16x2*)(AL + b * DD + d0) = pl;
    }
}

// ---------------- K4: MFMA GEMM  simc = 16 * inorm @ mnorm^T -----------------
// bf16 3-term split (Ah*Bh + Ah*Bl + Al*Bh), fp32 accum. 32x32 tiles ->
// 1024 blocks = 4 blocks/CU = 4 waves/SIMD for L2-latency hiding.
__global__ __launch_bounds__(256) void k_gemm(const bf16_t* __restrict__ AH,
                                              const bf16_t* __restrict__ AL,
                                              const bf16_t* __restrict__ BH,
                                              const bf16_t* __restrict__ BL,
                                              float* __restrict__ simc) {
    int wave = threadIdx.x >> 6;
    int lane = threadIdx.x & 63;
    int b0 = blockIdx.y * 32 + (wave >> 1) * 16;
    int k0 = blockIdx.x * 32 + (wave & 1) * 16;
    int frow = lane & 15;              // A-row / B-col within fragment
    int koff = (lane >> 4) * 8;        // k offset within fragment
    const bf16_t* pAh = AH + (size_t)(b0 + frow) * DD + koff;
    const bf16_t* pAl = AL + (size_t)(b0 + frow) * DD + koff;
    const bf16_t* pBh = BH + (size_t)(k0 + frow) * DD + koff;
    const bf16_t* pBl = BL + (size_t)(k0 + frow) * DD + koff;
    f32x4 acc = {};
    #pragma unroll 2
    for (int dk = 0; dk < DD; dk += 32) {
        bf16x8 ah = *(const bf16x8*)(pAh + dk);
        bf16x8 al = *(const bf16x8*)(pAl + dk);
        bf16x8 bh = *(const bf16x8*)(pBh + dk);
        bf16x8 bl = *(const bf16x8*)(pBl + dk);
        acc = __builtin_amdgcn_mfma_f32_16x16x32_bf16(ah, bh, acc, 0, 0, 0);
        acc = __builtin_amdgcn_mfma_f32_16x16x32_bf16(ah, bl, acc, 0, 0, 0);
        acc = __builtin_amdgcn_mfma_f32_16x16x32_bf16(al, bh, acc, 0, 0, 0);
    }
    // C/D layout: col = lane&15, row = (lane>>4)*4 + reg
    int r4 = (lane >> 4) * 4;
    int cn = lane & 15;
    #pragma unroll
    for (int r = 0; r < 4; ++r)
        simc[(size_t)(b0 + r4 + r) * KMAX + k0 + cn] = acc[r] * SCALE_F;
}

// ---------------- K5: fused gather (sorted, unrolled) + loss + final write ---
__global__ __launch_bounds__(256) void k_loss(const float* __restrict__ simc,
                                              const float* __restrict__ pm,
                                              const int* __restrict__ sc,
                                              const int* __restrict__ rowrank,
                                              const int* __restrict__ kctr,
                                              float* lossAcc, int* doneCtr,
                                              float* outp) {
    int b = blockIdx.x;
    int tid = threadIdx.x;
    int Kv = *kctr; if (Kv > KMAX) Kv = KMAX;
    __shared__ float pm_s[KMAX];
    __shared__ float s_s[KMAX];
    __shared__ int sc_s[KMAX];
    __shared__ float r1[256], r2[256];
    const float* __restrict__ row = pm + (size_t)b * CC;
    const float* __restrict__ srow = simc + (size_t)b * KMAX;
    for (int k = tid; k < Kv; k += 256) {
        sc_s[k] = sc[k];               // coalesced, L2-hot
        s_s[k] = srow[k];              // coalesced
    }
    __syncthreads();
    // 4 independent predicated gathers (ascending columns -> DRAM-sequential)
    {
        int k0 = tid, k1 = tid + 256, k2 = tid + 512, k3 = tid + 768;
        float v0 = 0.0f, v1 = 0.0f, v2 = 0.0f, v3 = 0.0f;
        if (k0 < Kv) v0 = row[sc_s[k0]];
        if (k1 < Kv) v1 = row[sc_s[k1]];
        if (k2 < Kv) v2 = row[sc_s[k2]];
        if (k3 < Kv) v3 = row[sc_s[k3]];
        if (k0 < Kv) pm_s[k0] = v0;
        if (k1 < Kv) pm_s[k1] = v1;
        if (k2 < Kv) pm_s[k2] = v2;
        if (k3 < Kv) pm_s[k3] = v3;
    }
    int rt = rowrank[b];
    __syncthreads();

    float sneg = 0.0f, psum = 0.0f;
    for (int k = tid; k < Kv; k += 256) {
        sneg += (1.0f - pm_s[k]) * expf(s_s[k]);
        psum += pm_s[k];
    }
    r1[tid] = sneg; r2[tid] = psum;
    __syncthreads();
    for (int s = 128; s > 0; s >>= 1) {
        if (tid < s) { r1[tid] += r1[tid + s]; r2[tid] += r2[tid + s]; }
        __syncthreads();
    }
    sneg = r1[0]; psum = r2[0];
    __syncthreads();

    float inv = EPS_F / psum;
    float acc = 0.0f;
    for (int k = tid; k < Kv; k += 256) {
        float w = inv * pm_s[k] + ((k == rt) ? (1.0f - EPS_F) : 0.0f);
        if (w != 0.0f)                 // ~2-3 per row: recompute exp is cheap
            acc += w * (s_s[k] - logf(sneg + expf(s_s[k])));
    }
    r1[tid] = acc;
    __syncthreads();
    for (int s = 128; s > 0; s >>= 1) {
        if (tid < s) r1[tid] += r1[tid + s];
        __syncthreads();
    }
    if (tid == 0) {
        atomicAdd(lossAcc, -r1[0] * (1.0f / BB));
        __threadfence();
        int done = atomicAdd(doneCtr, 1);
        if (done == BB - 1)
            outp[0] = atomicAdd(lossAcc, 0.0f);   // atomic read-back
    }
}

extern "C" void kernel_launch(void* const* d_in, const int* in_sizes, int n_in,
                              void* d_out, int out_size, void* d_ws, size_t ws_size,
                              hipStream_t stream) {
    const float* inputs  = (const float*)d_in[0];
    const float* pmask   = (const float*)d_in[1];
    const float* fmem    = (const float*)d_in[2];
    const int*   lmem    = (const int*)d_in[3];
    const int*   targets = (const int*)d_in[4];
    float* outp = (float*)d_out;

    char* ws = (char*)d_ws;
    size_t off = 0;
    auto alloc = [&](size_t bytes) -> void* {
        void* p = ws + off;
        off = (off + bytes + 255) & ~(size_t)255;
        return p;
    };
    int*    gkey    = (int*)alloc(HSZ * sizeof(int));
    int*    sc      = (int*)alloc(KMAX * sizeof(int));
    int*    rowrank = (int*)alloc(BB * sizeof(int));
    int*    kctr    = (int*)alloc(sizeof(int));
    int*    doneCtr = (int*)alloc(sizeof(int));
    float*  lossAcc = (float*)alloc(sizeof(float));
    bf16_t* AH      = (bf16_t*)alloc((size_t)BB * DD * sizeof(bf16_t));
    bf16_t* AL      = (bf16_t*)alloc((size_t)BB * DD * sizeof(bf16_t));
    bf16_t* BH      = (bf16_t*)alloc((size_t)KMAX * DD * sizeof(bf16_t));
    bf16_t* BL      = (bf16_t*)alloc((size_t)KMAX * DD * sizeof(bf16_t));
    float*  simc    = (float*)alloc((size_t)BB * KMAX * sizeof(float));

    k_prep<<<1, 1024, 0, stream>>>(targets, gkey, sc, rowrank, kctr, lossAcc, doneCtr);
    k_scan<<<(CC + 255) / 256, 256, 0, stream>>>(lmem, gkey, sc, kctr);
    k_norm<<<2 * KMAX, 256, 0, stream>>>(inputs, fmem, targets, sc, kctr, AH, AL, BH, BL);
    dim3 g4(KMAX / 32, BB / 32);
    k_gemm<<<g4, 256, 0, stream>>>(AH, AL, BH, BL, simc);
    k_loss<<<BB, 256, 0, stream>>>(simc, pmask, sc, rowrank, kctr, lossAcc, doneCtr, outp);
}

// Round 6
// 78.408 us; speedup vs baseline: 1.1965x; 1.1965x over previous
//
#include <hip/hip_runtime.h>
#include <math.h>

#define BB 1024      // batch
#define DD 512       // feature dim
#define CC 50000     // classes
#define KMAX 1024    // max compacted classes
#define HSZ 2048     // hash size
#define SCALE_F 16.0f
#define EPS_F 0.1f

typedef __bf16 bf16_t;
typedef bf16_t bf16x2 __attribute__((ext_vector_type(2)));
typedef bf16_t bf16x8 __attribute__((ext_vector_type(8)));
typedef float f32x4 __attribute__((ext_vector_type(4)));

// ---------------- K1: dedup targets via LDS hash (single block) --------------
__global__ __launch_bounds__(1024) void k_prep(const int* __restrict__ targets,
                                               int* gkey, int* sc, int* rowrank,
                                               int* kctr, int* doneCtr) {
    __shared__ int hkey[HSZ];
    __shared__ int hval[HSZ];
    __shared__ int kc;
    int tid = threadIdx.x;
    hkey[tid] = -1; hkey[tid + 1024] = -1;
    if (tid == 0) kc = 0;
    __syncthreads();
    int c = targets[tid];
    unsigned h = ((unsigned)c * 2654435761u) >> 21;   // 0..2047
    int myslot;
    while (true) {
        int old = atomicCAS(&hkey[h], -1, c);
        if (old == -1) {                  // owner: assign rank
            int r = atomicAdd(&kc, 1);
            hval[h] = r;
            sc[r] = c;
            myslot = (int)h;
            break;
        } else if (old == c) { myslot = (int)h; break; }
        h = (h + 1) & (HSZ - 1);
    }
    __syncthreads();                      // hval writes visible to all
    rowrank[tid] = hval[myslot];
    gkey[tid] = hkey[tid]; gkey[tid + 1024] = hkey[tid + 1024];
    if (tid == 0) { *kctr = kc; *doneCtr = 0; }
}

// ---------------- K2: parallel lmem scan (appends non-target valid classes) --
__global__ void k_scan(const int* __restrict__ lmem,
                       const int* __restrict__ gkey,
                       int* sc, int* kctr) {
    int c = blockIdx.x * blockDim.x + threadIdx.x;
    if (c >= CC) return;
    if (lmem[c] == -1) return;            // all -1 in this workload: fast path
    unsigned h = ((unsigned)c * 2654435761u) >> 21;
    while (true) {
        int k = gkey[h];
        if (k == c) return;               // already ranked as a target class
        if (k == -1) break;               // absent from target set
        h = (h + 1) & (HSZ - 1);
    }
    int slot = atomicAdd(kctr, 1);
    if (slot < KMAX) sc[slot] = c;
}

// ---------------- K3: merged normalize (classes + rows) + bf16 hi/lo split ---
__global__ __launch_bounds__(256) void k_norm(const float* __restrict__ inputs,
                                              const float* __restrict__ fmem,
                                              const int* __restrict__ targets,
                                              const int* __restrict__ sc,
                                              const int* __restrict__ kctr,
                                              bf16_t* __restrict__ AH,
                                              bf16_t* __restrict__ AL,
                                              bf16_t* __restrict__ BH,
                                              bf16_t* __restrict__ BL) {
    int blk = blockIdx.x;
    int tid = threadIdx.x;
    int d0 = tid * 2;
    __shared__ float red[256];
    if (blk < KMAX) {
        // ---- class path: segment mean (sum; /count cancels) + normalize ----
        int k = blk;
        int Kv = *kctr; if (Kv > KMAX) Kv = KMAX;
        if (k >= Kv) {                    // zero-pad so GEMM reads zeros
            bf16x2 z; z[0] = (bf16_t)0.0f; z[1] = (bf16_t)0.0f;
            *(bf16x2*)(BH + k * DD + d0) = z;
            *(bf16x2*)(BL + k * DD + d0) = z;
            return;
        }
        int c = sc[k];
        __shared__ int members[BB];
        __shared__ int mcount;
        if (tid == 0) mcount = 0;
        __syncthreads();
        int4 t4 = *(const int4*)(targets + tid * 4);
        if (t4.x == c) { int s = atomicAdd(&mcount, 1); members[s] = tid * 4 + 0; }
        if (t4.y == c) { int s = atomicAdd(&mcount, 1); members[s] = tid * 4 + 1; }
        if (t4.z == c) { int s = atomicAdd(&mcount, 1); members[s] = tid * 4 + 2; }
        if (t4.w == c) { int s = atomicAdd(&mcount, 1); members[s] = tid * 4 + 3; }
        __syncthreads();
        int mc = mcount;
        float a0 = 0.0f, a1 = 0.0f;
        if (mc == 0) {                    // lmem-only class: memory row
            a0 = fmem[(size_t)c * DD + d0];
            a1 = fmem[(size_t)c * DD + d0 + 1];
        } else {
            for (int i = 0; i < mc; ++i) {
                int b = members[i];
                a0 += inputs[b * DD + d0];
                a1 += inputs[b * DD + d0 + 1];
            }
        }
        red[tid] = a0 * a0 + a1 * a1;
        __syncthreads();
        for (int s = 128; s > 0; s >>= 1) {
            if (tid < s) red[tid] += red[tid + s];
            __syncthreads();
        }
        float scale = 1.0f / fmaxf(sqrtf(red[0]), 1e-12f);
        a0 *= scale; a1 *= scale;
        bf16_t h0 = (bf16_t)a0, h1 = (bf16_t)a1;
        bf16x2 ph; ph[0] = h0; ph[1] = h1;
        bf16x2 pl; pl[0] = (bf16_t)(a0 - (float)h0); pl[1] = (bf16_t)(a1 - (float)h1);
        *(bf16x2*)(BH + k * DD + d0) = ph;
        *(bf16x2*)(BL + k * DD + d0) = pl;
    } else {
        // ---- row path: normalize input row ----
        int b = blk - KMAX;
        float a0 = inputs[b * DD + d0];
        float a1 = inputs[b * DD + d0 + 1];
        red[tid] = a0 * a0 + a1 * a1;
        __syncthreads();
        for (int s = 128; s > 0; s >>= 1) {
            if (tid < s) red[tid] += red[tid + s];
            __syncthreads();
        }
        float scale = 1.0f / fmaxf(sqrtf(red[0]), 1e-12f);
        a0 *= scale; a1 *= scale;
        bf16_t h0 = (bf16_t)a0, h1 = (bf16_t)a1;
        bf16x2 ph; ph[0] = h0; ph[1] = h1;
        bf16x2 pl; pl[0] = (bf16_t)(a0 - (float)h0); pl[1] = (bf16_t)(a1 - (float)h1);
        *(bf16x2*)(AH + b * DD + d0) = ph;
        *(bf16x2*)(AL + b * DD + d0) = pl;
    }
}

// ---------------- K4: MIXED dispatch — pm gather (HBM) + MFMA GEMM (compute) -
// blocks [0,1024): gather pm row b at seen columns -> pmc[b][k] (the HBM-bound
// long pole). blocks [1024,1280): 64x64 GEMM tiles (bf16 3-term split, fp32
// accum, L2-resident operands). Both depend only on earlier dispatches; they
// co-schedule across CUs so dispatch time ~= max(gather, gemm), not the sum.
__global__ __launch_bounds__(256) void k_mix(const float* __restrict__ pm,
                                             const int* __restrict__ sc,
                                             const int* __restrict__ kctr,
                                             const bf16_t* __restrict__ AH,
                                             const bf16_t* __restrict__ AL,
                                             const bf16_t* __restrict__ BH,
                                             const bf16_t* __restrict__ BL,
                                             float* __restrict__ pmc,
                                             float* __restrict__ simc) {
    int bid = blockIdx.x;
    int tid = threadIdx.x;
    if (bid < BB) {
        // ---- gather part ----
        int Kv = *kctr; if (Kv > KMAX) Kv = KMAX;
        const float* __restrict__ row = pm + (size_t)bid * CC;
        float* __restrict__ dst = pmc + (size_t)bid * KMAX;
        int k0 = tid, k1 = tid + 256, k2 = tid + 512, k3 = tid + 768;
        int c0 = 0, c1 = 0, c2 = 0, c3 = 0;
        if (k0 < Kv) c0 = sc[k0];
        if (k1 < Kv) c1 = sc[k1];
        if (k2 < Kv) c2 = sc[k2];
        if (k3 < Kv) c3 = sc[k3];
        float v0 = 0.0f, v1 = 0.0f, v2 = 0.0f, v3 = 0.0f;
        if (k0 < Kv) v0 = row[c0];
        if (k1 < Kv) v1 = row[c1];
        if (k2 < Kv) v2 = row[c2];
        if (k3 < Kv) v3 = row[c3];
        if (k0 < Kv) dst[k0] = v0;
        if (k1 < Kv) dst[k1] = v1;
        if (k2 < Kv) dst[k2] = v2;
        if (k3 < Kv) dst[k3] = v3;
    } else {
        // ---- GEMM part: 64x64 tile, 4 waves, each a 32x32 quadrant ----
        int t = bid - BB;
        int wave = tid >> 6;
        int lane = tid & 63;
        int b0 = (t >> 4) * 64 + (wave >> 1) * 32;
        int k0 = (t & 15) * 64 + (wave & 1) * 32;
        int frow = lane & 15;
        int koff = (lane >> 4) * 8;
        f32x4 acc[2][2] = {};
        #pragma unroll 2
        for (int dk = 0; dk < DD; dk += 32) {
            bf16x8 ah[2], al[2], bh[2], bl[2];
            #pragma unroll
            for (int i = 0; i < 2; ++i) {
                size_t ao = (size_t)(b0 + i * 16 + frow) * DD + dk + koff;
                size_t bo = (size_t)(k0 + i * 16 + frow) * DD + dk + koff;
                ah[i] = *(const bf16x8*)(AH + ao);
                al[i] = *(const bf16x8*)(AL + ao);
                bh[i] = *(const bf16x8*)(BH + bo);
                bl[i] = *(const bf16x8*)(BL + bo);
            }
            #pragma unroll
            for (int mi = 0; mi < 2; ++mi)
                #pragma unroll
                for (int ni = 0; ni < 2; ++ni) {
                    acc[mi][ni] = __builtin_amdgcn_mfma_f32_16x16x32_bf16(ah[mi], bh[ni], acc[mi][ni], 0, 0, 0);
                    acc[mi][ni] = __builtin_amdgcn_mfma_f32_16x16x32_bf16(ah[mi], bl[ni], acc[mi][ni], 0, 0, 0);
                    acc[mi][ni] = __builtin_amdgcn_mfma_f32_16x16x32_bf16(al[mi], bh[ni], acc[mi][ni], 0, 0, 0);
                }
        }
        // C/D layout: col = lane&15, row = (lane>>4)*4 + reg
        int r4 = (lane >> 4) * 4;
        int cn = lane & 15;
        #pragma unroll
        for (int mi = 0; mi < 2; ++mi)
            #pragma unroll
            for (int ni = 0; ni < 2; ++ni)
                #pragma unroll
                for (int r = 0; r < 4; ++r)
                    simc[(size_t)(b0 + mi * 16 + r4 + r) * KMAX + (k0 + ni * 16 + cn)]
                        = acc[mi][ni][r] * SCALE_F;
    }
}

// ---------------- K5: per-row loss (coalesced) + last-block final reduce -----
__global__ __launch_bounds__(256) void k_loss(const float* __restrict__ simc,
                                              const float* __restrict__ pmc,
                                              const int* __restrict__ rowrank,
                                              const int* __restrict__ kctr,
                                              float* partials, int* doneCtr,
                                              float* outp) {
    int b = blockIdx.x;
    int tid = threadIdx.x;
    int Kv = *kctr; if (Kv > KMAX) Kv = KMAX;
    __shared__ float s_s[KMAX];
    __shared__ float p_s[KMAX];
    __shared__ float r1[256], r2[256];
    __shared__ int isLast;
    const float* __restrict__ srow = simc + (size_t)b * KMAX;
    const float* __restrict__ prow = pmc + (size_t)b * KMAX;
    for (int k = tid; k < Kv; k += 256) { s_s[k] = srow[k]; p_s[k] = prow[k]; }
    int rt = rowrank[b];
    __syncthreads();

    float sneg = 0.0f, psum = 0.0f;
    for (int k = tid; k < Kv; k += 256) {
        float pmv = p_s[k];
        sneg += (1.0f - pmv) * expf(s_s[k]);
        psum += pmv;
    }
    r1[tid] = sneg; r2[tid] = psum;
    __syncthreads();
    for (int s = 128; s > 0; s >>= 1) {
        if (tid < s) { r1[tid] += r1[tid + s]; r2[tid] += r2[tid + s]; }
        __syncthreads();
    }
    sneg = r1[0]; psum = r2[0];
    __syncthreads();

    float inv = EPS_F / psum;
    float acc = 0.0f;
    for (int k = tid; k < Kv; k += 256) {
        float w = inv * p_s[k] + ((k == rt) ? (1.0f - EPS_F) : 0.0f);
        if (w != 0.0f)                 // ~2-3 nonzero per row
            acc += w * (s_s[k] - logf(sneg + expf(s_s[k])));
    }
    r1[tid] = acc;
    __syncthreads();
    for (int s = 128; s > 0; s >>= 1) {
        if (tid < s) r1[tid] += r1[tid + s];
        __syncthreads();
    }
    if (tid == 0) {
        partials[b] = r1[0];
        __threadfence();
        isLast = (atomicAdd(doneCtr, 1) == BB - 1);
    }
    __syncthreads();
    if (isLast) {                      // last finishing block: final reduce
        float a = 0.0f;
        for (int i = tid; i < BB; i += 256) a += partials[i];
        r1[tid] = a;
        __syncthreads();
        for (int s = 128; s > 0; s >>= 1) {
            if (tid < s) r1[tid] += r1[tid + s];
            __syncthreads();
        }
        if (tid == 0) outp[0] = -r1[0] * (1.0f / BB);
    }
}

extern "C" void kernel_launch(void* const* d_in, const int* in_sizes, int n_in,
                              void* d_out, int out_size, void* d_ws, size_t ws_size,
                              hipStream_t stream) {
    const float* inputs  = (const float*)d_in[0];
    const float* pmask   = (const float*)d_in[1];
    const float* fmem    = (const float*)d_in[2];
    const int*   lmem    = (const int*)d_in[3];
    const int*   targets = (const int*)d_in[4];
    float* outp = (float*)d_out;

    char* ws = (char*)d_ws;
    size_t off = 0;
    auto alloc = [&](size_t bytes) -> void* {
        void* p = ws + off;
        off = (off + bytes + 255) & ~(size_t)255;
        return p;
    };
    int*    gkey     = (int*)alloc(HSZ * sizeof(int));
    int*    sc       = (int*)alloc(KMAX * sizeof(int));
    int*    rowrank  = (int*)alloc(BB * sizeof(int));
    int*    kctr     = (int*)alloc(sizeof(int));
    int*    doneCtr  = (int*)alloc(sizeof(int));
    float*  partials = (float*)alloc(BB * sizeof(float));
    bf16_t* AH       = (bf16_t*)alloc((size_t)BB * DD * sizeof(bf16_t));
    bf16_t* AL       = (bf16_t*)alloc((size_t)BB * DD * sizeof(bf16_t));
    bf16_t* BH       = (bf16_t*)alloc((size_t)KMAX * DD * sizeof(bf16_t));
    bf16_t* BL       = (bf16_t*)alloc((size_t)KMAX * DD * sizeof(bf16_t));
    float*  pmc      = (float*)alloc((size_t)BB * KMAX * sizeof(float));
    float*  simc     = (float*)alloc((size_t)BB * KMAX * sizeof(float));

    k_prep<<<1, 1024, 0, stream>>>(targets, gkey, sc, rowrank, kctr, doneCtr);
    k_scan<<<(CC + 255) / 256, 256, 0, stream>>>(lmem, gkey, sc, kctr);
    k_norm<<<2 * KMAX, 256, 0, stream>>>(inputs, fmem, targets, sc, kctr, AH, AL, BH, BL);
    k_mix<<<BB + 256, 256, 0, stream>>>(pmask, sc, kctr, AH, AL, BH, BL, pmc, simc);
    k_loss<<<BB, 256, 0, stream>>>(simc, pmc, rowrank, kctr, partials, doneCtr, outp);
}